// Round 1
// baseline (142.920 us; speedup 1.0000x reference)
//
#include <hip/hip_runtime.h>

#define GS 26            // grid size S
#define NBOX 3
#define NCLS 80
#define BATCH 128
#define NTGT_PER 50
#define CELLS (GS * GS)              // 676
#define CHTOT (NBOX * (5 + NCLS))    // 255
#define NT (BATCH * NTGT_PER)        // 6400
#define NCELL (BATCH * CELLS)        // 86528
#define L_COORD 5.0f
#define L_NOOBJ 0.5f

// Kernel 1: mark cells that contain a valid target (box 0 responsibility mask).
__global__ void yolo_scatter_obj(const float* __restrict__ tgt,
                                 unsigned char* __restrict__ obj) {
    int t = blockIdx.x * blockDim.x + threadIdx.x;
    if (t >= NT) return;
    const float* tp = tgt + (size_t)t * 5;
    float cx = tp[1], cy = tp[2];
    int gx = (int)(cx * GS);   // trunc, matches .astype(int32)
    int gy = (int)(cy * GS);
    if (gx < GS && gy < GS) {  // reference valid check: upper bound only
        int gxc = min(max(gx, 0), GS - 1);
        int gyc = min(max(gy, 0), GS - 1);
        int b = t / NTGT_PER;
        obj[b * CELLS + gyc * GS + gxc] = 1;  // idempotent; races benign
    }
}

// Kernel 2: fused no-obj confidence loss + per-target coord/class loss.
__global__ void yolo_loss(const float* __restrict__ pred,
                          const float* __restrict__ tgt,
                          const unsigned char* __restrict__ obj,
                          float* __restrict__ out) {
    int idx = blockIdx.x * blockDim.x + threadIdx.x;
    float acc = 0.0f;

    // --- no-object confidence term: one thread per (b, cell) ---
    if (idx < NCELL) {
        int b = idx / CELLS;
        int cell = idx - b * CELLS;
        const float* base = pred + (size_t)b * CHTOT * CELLS + cell;
        float c0 = base[0];                         // box0 conf, channel 0
        float c1 = base[(size_t)(1 * (5 + NCLS)) * CELLS];   // channel 85
        float c2 = base[(size_t)(2 * (5 + NCLS)) * CELLS];   // channel 170
        float no0 = obj[idx] ? 0.0f : 1.0f;         // only box0 is ever marked
        acc += L_NOOBJ * (c0 * c0 * no0 + c1 * c1 + c2 * c2);
    }

    // --- per-target coord + class term: first NT threads ---
    if (idx < NT) {
        const float* tp = tgt + (size_t)idx * 5;
        float cls = tp[0], cx = tp[1], cy = tp[2], w = tp[3], h = tp[4];
        int gx = (int)(cx * GS);
        int gy = (int)(cy * GS);
        if (gx < GS && gy < GS) {
            int gxc = min(max(gx, 0), GS - 1);
            int gyc = min(max(gy, 0), GS - 1);
            int b = idx / NTGT_PER;
            const float* pb = pred + (size_t)b * CHTOT * CELLS + gyc * GS + gxc;
            // channels 1..4: coord
            float d1 = pb[1 * CELLS] - cx;
            float d2 = pb[2 * CELLS] - cy;
            float d3 = pb[3 * CELLS] - w;
            float d4 = pb[4 * CELLS] - h;
            float coord = d1 * d1 + d2 * d2 + d3 * d3 + d4 * d4;
            // channels 5..84: class MSE vs one-hot
            int ci = (int)cls;
            float clsum = 0.0f;
            #pragma unroll
            for (int c = 0; c < NCLS; ++c) {
                float v = pb[(size_t)(5 + c) * CELLS] - ((c == ci) ? 1.0f : 0.0f);
                clsum += v * v;
            }
            acc += L_COORD * coord + clsum;
        }
    }

    // --- block reduction: wave shuffle (64 lanes) then LDS across 4 waves ---
    #pragma unroll
    for (int off = 32; off > 0; off >>= 1)
        acc += __shfl_down(acc, off);
    __shared__ float ws[4];
    int lane = threadIdx.x & 63;
    int wid = threadIdx.x >> 6;
    if (lane == 0) ws[wid] = acc;
    __syncthreads();
    if (threadIdx.x == 0) {
        float v = ws[0] + ws[1] + ws[2] + ws[3];
        atomicAdd(out, v * (1.0f / BATCH));
    }
}

extern "C" void kernel_launch(void* const* d_in, const int* in_sizes, int n_in,
                              void* d_out, int out_size, void* d_ws, size_t ws_size,
                              hipStream_t stream) {
    const float* pred = (const float*)d_in[0];
    const float* tgt  = (const float*)d_in[1];
    float* out = (float*)d_out;
    unsigned char* obj = (unsigned char*)d_ws;

    // zero the obj mask and the output accumulator (ws/out are poisoned 0xAA)
    hipMemsetAsync(obj, 0, NCELL, stream);
    hipMemsetAsync(out, 0, sizeof(float), stream);

    yolo_scatter_obj<<<(NT + 255) / 256, 256, 0, stream>>>(tgt, obj);

    int blocks = (NCELL + 255) / 256;  // 338
    yolo_loss<<<blocks, 256, 0, stream>>>(pred, tgt, obj, out);
}

// Round 2
// 129.644 us; speedup vs baseline: 1.1024x; 1.1024x over previous
//
#include <hip/hip_runtime.h>

#define GS 26            // grid size S
#define NBOX 3
#define NCLS 80
#define BATCH 128
#define NTGT_PER 50
#define CELLS (GS * GS)              // 676
#define CH (5 + NCLS)                // 85
#define CHTOT (NBOX * CH)            // 255
#define L_COORD 5.0f
#define L_NOOBJ 0.5f

// One block per batch image. Builds the obj mask in LDS from the image's 50
// targets, then computes the no-obj confidence term (coalesced plane reads)
// and the per-target coord+class term (gather parallelized across lanes).
__global__ __launch_bounds__(256) void yolo_fused(const float* __restrict__ pred,
                                                  const float* __restrict__ tgt,
                                                  float* __restrict__ out) {
    const int b   = blockIdx.x;
    const int tid = threadIdx.x;

    __shared__ float         stgt[NTGT_PER * 5];   // this image's targets
    __shared__ unsigned char obj[CELLS];           // box-0 responsibility mask
    __shared__ float         wsum[4];

    // ---- stage targets + zero obj mask ----
    if (tid < NTGT_PER * 5) stgt[tid] = tgt[(size_t)b * NTGT_PER * 5 + tid];
    for (int i = tid; i < CELLS; i += 256) obj[i] = 0;
    __syncthreads();

    // ---- scatter obj (50 idempotent LDS writes) ----
    if (tid < NTGT_PER) {
        float cx = stgt[tid * 5 + 1], cy = stgt[tid * 5 + 2];
        int gx = (int)(cx * GS);   // trunc == reference .astype(int32) for cx>=0
        int gy = (int)(cy * GS);
        if (gx < GS && gy < GS) {  // reference: upper-bound-only validity
            int gxc = min(max(gx, 0), GS - 1);
            int gyc = min(max(gy, 0), GS - 1);
            obj[gyc * GS + gxc] = 1;
        }
    }
    __syncthreads();

    float acc = 0.0f;
    const float* pb0 = pred + (size_t)b * CHTOT * CELLS;

    // ---- no-obj confidence term: coalesced reads of planes 0/85/170 ----
    for (int cell = tid; cell < CELLS; cell += 256) {
        float c0 = pb0[cell];                       // box0 conf
        float c1 = pb0[(size_t)CH * CELLS + cell];  // box1 conf (never obj)
        float c2 = pb0[(size_t)2 * CH * CELLS + cell];
        float no0 = obj[cell] ? 0.0f : 1.0f;
        acc += L_NOOBJ * (c0 * c0 * no0 + c1 * c1 + c2 * c2);
    }

    // ---- per-target coord+class: wave w handles targets w, w+4, ... ----
    // lane j covers channels j and j+64 (j+64 < 85 only for j < 21).
    const int wid  = tid >> 6;
    const int lane = tid & 63;
    for (int t = wid; t < NTGT_PER; t += 4) {
        float cls = stgt[t * 5 + 0];
        float cx  = stgt[t * 5 + 1];
        float cy  = stgt[t * 5 + 2];
        float w   = stgt[t * 5 + 3];
        float h   = stgt[t * 5 + 4];
        int gx = (int)(cx * GS);
        int gy = (int)(cy * GS);
        if (gx >= GS || gy >= GS) continue;          // invalid target
        int gxc = min(max(gx, 0), GS - 1);
        int gyc = min(max(gy, 0), GS - 1);
        int ci  = (int)cls;
        const float* pb = pb0 + gyc * GS + gxc;      // channel j at pb[j*CELLS]

        #pragma unroll
        for (int rep = 0; rep < 2; ++rep) {
            int j = lane + rep * 64;                 // channel index 0..84
            if (j >= 1 && j < CH) {
                float p = pb[(size_t)j * CELLS];
                float tv, wgt;
                if (j <= 4) {
                    tv  = (j == 1) ? cx : (j == 2) ? cy : (j == 3) ? w : h;
                    wgt = L_COORD;
                } else {
                    tv  = (j - 5 == ci) ? 1.0f : 0.0f;
                    wgt = 1.0f;
                }
                float d = p - tv;
                acc += wgt * d * d;
            }
        }
    }

    // ---- block reduction: 64-lane shuffle, then LDS across 4 waves ----
    #pragma unroll
    for (int off = 32; off > 0; off >>= 1)
        acc += __shfl_down(acc, off);
    if (lane == 0) wsum[wid] = acc;
    __syncthreads();
    if (tid == 0) {
        float v = wsum[0] + wsum[1] + wsum[2] + wsum[3];
        atomicAdd(out, v * (1.0f / BATCH));
    }
}

extern "C" void kernel_launch(void* const* d_in, const int* in_sizes, int n_in,
                              void* d_out, int out_size, void* d_ws, size_t ws_size,
                              hipStream_t stream) {
    const float* pred = (const float*)d_in[0];
    const float* tgt  = (const float*)d_in[1];
    float* out = (float*)d_out;

    hipMemsetAsync(out, 0, sizeof(float), stream);  // d_out is poisoned 0xAA
    yolo_fused<<<BATCH, 256, 0, stream>>>(pred, tgt, out);
}

// Round 3
// 123.013 us; speedup vs baseline: 1.1618x; 1.0539x over previous
//
#include <hip/hip_runtime.h>

#define GS 26            // grid size S
#define NBOX 3
#define NCLS 80
#define BATCH 128
#define NTGT_PER 50
#define CELLS (GS * GS)              // 676
#define CH (5 + NCLS)                // 85
#define CHTOT (NBOX * CH)            // 255
#define L_COORD 5.0f
#define L_NOOBJ 0.5f

#define SPLIT 4                      // blocks per image
#define CPB ((CELLS + SPLIT - 1) / SPLIT)     // 169 cells per block
#define TPB ((NTGT_PER + SPLIT - 1) / SPLIT)  // 13 targets per block

// 4 blocks per batch image (512 blocks total = 2/CU). Each block: builds the
// full obj mask in LDS (cheap), handles 1/4 of the cells for the no-obj term
// and 1/4 of the targets for the coord+class gather.
__global__ __launch_bounds__(256) void yolo_fused(const float* __restrict__ pred,
                                                  const float* __restrict__ tgt,
                                                  float* __restrict__ out) {
    const int b   = blockIdx.x >> 2;       // image index
    const int q   = blockIdx.x & 3;        // quarter index
    const int tid = threadIdx.x;

    __shared__ float         stgt[NTGT_PER * 5];   // this image's targets
    __shared__ unsigned char obj[CELLS];           // box-0 responsibility mask
    __shared__ float         wsum[4];

    // ---- stage targets + zero obj mask ----
    if (tid < NTGT_PER * 5) stgt[tid] = tgt[(size_t)b * NTGT_PER * 5 + tid];
    for (int i = tid; i < CELLS; i += 256) obj[i] = 0;
    __syncthreads();

    // ---- scatter obj (50 idempotent LDS writes) ----
    if (tid < NTGT_PER) {
        float cx = stgt[tid * 5 + 1], cy = stgt[tid * 5 + 2];
        int gx = (int)(cx * GS);   // trunc == reference .astype(int32) for cx>=0
        int gy = (int)(cy * GS);
        if (gx < GS && gy < GS) {  // reference: upper-bound-only validity
            int gxc = min(max(gx, 0), GS - 1);
            int gyc = min(max(gy, 0), GS - 1);
            obj[gyc * GS + gxc] = 1;
        }
    }
    __syncthreads();

    float acc = 0.0f;
    const float* pb0 = pred + (size_t)b * CHTOT * CELLS;

    // ---- no-obj confidence term: this block's 169-cell slice, coalesced ----
    {
        int cell = q * CPB + tid;
        if (tid < CPB && cell < CELLS) {
            float c0 = pb0[cell];                       // box0 conf
            float c1 = pb0[(size_t)CH * CELLS + cell];  // box1 conf (never obj)
            float c2 = pb0[(size_t)2 * CH * CELLS + cell];
            float no0 = obj[cell] ? 0.0f : 1.0f;
            acc += L_NOOBJ * (c0 * c0 * no0 + c1 * c1 + c2 * c2);
        }
    }

    // ---- per-target coord+class: this block's ~13 targets, 4 waves ----
    // lane j covers channels j and j+64 (j+64 < 85 only for j < 21).
    const int wid  = tid >> 6;
    const int lane = tid & 63;
    const int t0 = q * TPB;
    const int t1 = min(t0 + TPB, NTGT_PER);
    for (int t = t0 + wid; t < t1; t += 4) {
        float cls = stgt[t * 5 + 0];
        float cx  = stgt[t * 5 + 1];
        float cy  = stgt[t * 5 + 2];
        float w   = stgt[t * 5 + 3];
        float h   = stgt[t * 5 + 4];
        int gx = (int)(cx * GS);
        int gy = (int)(cy * GS);
        if (gx >= GS || gy >= GS) continue;          // invalid target
        int gxc = min(max(gx, 0), GS - 1);
        int gyc = min(max(gy, 0), GS - 1);
        int ci  = (int)cls;
        const float* pb = pb0 + gyc * GS + gxc;      // channel j at pb[j*CELLS]

        #pragma unroll
        for (int rep = 0; rep < 2; ++rep) {
            int j = lane + rep * 64;                 // channel index 0..84
            if (j >= 1 && j < CH) {
                float p = pb[(size_t)j * CELLS];
                float tv, wgt;
                if (j <= 4) {
                    tv  = (j == 1) ? cx : (j == 2) ? cy : (j == 3) ? w : h;
                    wgt = L_COORD;
                } else {
                    tv  = (j - 5 == ci) ? 1.0f : 0.0f;
                    wgt = 1.0f;
                }
                float d = p - tv;
                acc += wgt * d * d;
            }
        }
    }

    // ---- block reduction: 64-lane shuffle, then LDS across 4 waves ----
    #pragma unroll
    for (int off = 32; off > 0; off >>= 1)
        acc += __shfl_down(acc, off);
    if (lane == 0) wsum[wid] = acc;
    __syncthreads();
    if (tid == 0) {
        float v = wsum[0] + wsum[1] + wsum[2] + wsum[3];
        atomicAdd(out, v * (1.0f / BATCH));
    }
}

extern "C" void kernel_launch(void* const* d_in, const int* in_sizes, int n_in,
                              void* d_out, int out_size, void* d_ws, size_t ws_size,
                              hipStream_t stream) {
    const float* pred = (const float*)d_in[0];
    const float* tgt  = (const float*)d_in[1];
    float* out = (float*)d_out;

    hipMemsetAsync(out, 0, sizeof(float), stream);  // d_out is poisoned 0xAA
    yolo_fused<<<BATCH * SPLIT, 256, 0, stream>>>(tgt ? pred : pred, tgt, out);
}